// Round 3
// baseline (128.889 us; speedup 1.0000x reference)
//
#include <hip/hip_runtime.h>

#define K_CW 256
#define PPT 4       // points per thread: 72 VALU-cycles ILP per codeword fetch

struct P8 { float4 a; float4 b; };  // {c0,c1,c2,c3} {csq,pad,pad,pad} -> one s_load_dwordx8

// Build packed codebook in ws. csq uses numpy rounding:
// ((c0*c0 + c1*c1) + c2*c2) + c3*c3  (sequential adds of rounded squares)
__global__ void vq_pack_kernel(const float* __restrict__ tlut, float* __restrict__ pk) {
    int k = threadIdx.x;  // 256 threads, 1 block
    float c0 = tlut[k * 4 + 0];
    float c1 = tlut[k * 4 + 1];
    float c2 = tlut[k * 4 + 2];
    float c3 = tlut[k * 4 + 3];
    float s = __fadd_rn(__fadd_rn(__fadd_rn(__fmul_rn(c0, c0), __fmul_rn(c1, c1)),
                                  __fmul_rn(c2, c2)),
                        __fmul_rn(c3, c3));
    pk[k * 8 + 0] = c0; pk[k * 8 + 1] = c1; pk[k * 8 + 2] = c2; pk[k * 8 + 3] = c3;
    pk[k * 8 + 4] = s;  pk[k * 8 + 5] = 0.f; pk[k * 8 + 6] = 0.f; pk[k * 8 + 7] = 0.f;
}

__global__ __launch_bounds__(256, 4) void vq_argmin_kernel(
    const float* __restrict__ X,
    const float* __restrict__ tlut,
    const float* __restrict__ pk,
    float* __restrict__ outX,   // [B,4] reconstruction
    float* __restrict__ outS,   // [B] state, stored as float
    int B) {
    // No split-K: each thread scans all 256 codewords for 4 points.
    // 1024 blocks x 256 thr = 4 blocks/CU, ALL resident in one round
    // (16 waves/CU), no LDS, no barrier, no merge epilogue.
    const int g = blockIdx.x * 256 + threadIdx.x;   // point-group id
    const int stride = B / PPT;                     // strided points -> coalesced

    const float4* __restrict__ X4 = reinterpret_cast<const float4*>(X);
    const float4* __restrict__ T4 = reinterpret_cast<const float4*>(tlut);
    const P8* __restrict__ PK = reinterpret_cast<const P8*>(pk);

    float x0[PPT], x1[PPT], x2[PPT], x3[PPT], xsq[PPT], bestd[PPT];
    int besti[PPT];

    #pragma unroll
    for (int i = 0; i < PPT; ++i) {
        const float4 xv = X4[g + i * stride];
        x0[i] = xv.x; x1[i] = xv.y; x2[i] = xv.z; x3[i] = xv.w;
        // x_sq with numpy rounding: sequential adds of rounded squares
        xsq[i] = __fadd_rn(__fadd_rn(__fadd_rn(__fmul_rn(xv.x, xv.x), __fmul_rn(xv.y, xv.y)),
                                     __fmul_rn(xv.z, xv.z)),
                           __fmul_rn(xv.w, xv.w));
        bestd[i] = __builtin_inff();
        besti[i] = 0;
    }

    // Round-0-proven inner loop: wave-uniform k -> one s_load_dwordx8 per k,
    // compiler hoists batches of scalar loads across the unroll window.
    #pragma unroll 16
    for (int k = 0; k < K_CW; ++k) {
        const P8 e = PK[k];
        const float4 c = e.a;
        const float cs = e.b.x;
        #pragma unroll
        for (int i = 0; i < PPT; ++i) {
            // cross: numpy einsum `accum += a*b` with fp-contract -> ascending FMA chain
            float cross = __fmul_rn(x0[i], c.x);
            cross = __fmaf_rn(x1[i], c.y, cross);
            cross = __fmaf_rn(x2[i], c.z, cross);
            cross = __fmaf_rn(x3[i], c.w, cross);
            // (x_sq - 2*cross) + c_sq ; fma(-2,cross,xsq) == rn(xsq - rn(2*cross)) exactly
            float t2 = __fmaf_rn(-2.0f, cross, xsq[i]);
            float d = __fadd_rn(t2, cs);
            // argmin, first occurrence (strict <), ascending k
            besti[i] = (d < bestd[i]) ? k : besti[i];
            bestd[i] = fminf(d, bestd[i]);
        }
    }

    #pragma unroll
    for (int i = 0; i < PPT; ++i) {
        const int p = g + i * stride;
        reinterpret_cast<float4*>(outX)[p] = T4[besti[i]];  // tlut is L1-resident
        outS[p] = (float)besti[i];
    }
}

extern "C" void kernel_launch(void* const* d_in, const int* in_sizes, int n_in,
                              void* d_out, int out_size, void* d_ws, size_t ws_size,
                              hipStream_t stream) {
    const float* X    = (const float*)d_in[0];   // [B,4]
    const float* tlut = (const float*)d_in[1];   // [256,4]
    const int B = in_sizes[0] / 4;

    float* outX = (float*)d_out;          // first B*4 floats: hatX
    float* outS = outX + (size_t)B * 4;   // next B floats: state (as float)

    float* pk = (float*)d_ws;             // 256*8 floats packed codebook

    vq_pack_kernel<<<1, 256, 0, stream>>>(tlut, pk);

    const int groups = B / PPT;           // 262144 point-groups
    const int grid = groups / 256;        // 1024 blocks of 256 threads
    vq_argmin_kernel<<<grid, 256, 0, stream>>>(X, tlut, pk, outX, outS, B);
}

// Round 4
// 117.666 us; speedup vs baseline: 1.0954x; 1.0954x over previous
//
#include <hip/hip_runtime.h>

#define K_CW 256
#define PPT 4           // points per thread
#define NH 2            // split-K halves
#define KH (K_CW / NH)  // 128 k per half

struct P8 { float4 a; float4 b; };  // {c0,c1,c2,c3} {csq,pad,pad,pad} -> one s_load_dwordx8

// Build packed codebook in ws. csq uses numpy rounding:
// ((c0*c0 + c1*c1) + c2*c2) + c3*c3  (sequential adds of rounded squares)
__global__ void vq_pack_kernel(const float* __restrict__ tlut, float* __restrict__ pk) {
    int k = threadIdx.x;  // 256 threads, 1 block
    float c0 = tlut[k * 4 + 0];
    float c1 = tlut[k * 4 + 1];
    float c2 = tlut[k * 4 + 2];
    float c3 = tlut[k * 4 + 3];
    float s = __fadd_rn(__fadd_rn(__fadd_rn(__fmul_rn(c0, c0), __fmul_rn(c1, c1)),
                                  __fmul_rn(c2, c2)),
                        __fmul_rn(c3, c3));
    pk[k * 8 + 0] = c0; pk[k * 8 + 1] = c1; pk[k * 8 + 2] = c2; pk[k * 8 + 3] = c3;
    pk[k * 8 + 4] = s;  pk[k * 8 + 5] = 0.f; pk[k * 8 + 6] = 0.f; pk[k * 8 + 7] = 0.f;
}

__global__ __launch_bounds__(512, 8) void vq_argmin_kernel(
    const float* __restrict__ X,
    const float* __restrict__ tlut,
    const float* __restrict__ pk,
    float* __restrict__ outX,   // [B,4] reconstruction
    float* __restrict__ outS,   // [B] state, stored as float
    int B) {
    // split-K x2: half q scans k in [128q, 128q+128) on the same 4 points.
    // 1024 blocks x 512 thr = 8192 waves = 32 waves/CU, 4 blocks/CU, ALL
    // resident in one round. 8 waves/SIMD cover the s_load drain stalls.
    __shared__ float sd[PPT][256];  // upper half's bestd, separate b32 arrays
    __shared__ int   si[PPT][256];  // upper half's besti (2 lanes/bank = free)

    const int t = threadIdx.x;
    const int tt = t & 255;
    const int q = t >> 8;  // 0 or 1, wave-uniform (wave = 64 consecutive threads)
    const int kbase = __builtin_amdgcn_readfirstlane(q << 7);  // 0 or 128

    const int g = blockIdx.x * 256 + tt;   // point-group id
    const int stride = B / PPT;            // strided points -> coalesced

    const float4* __restrict__ X4 = reinterpret_cast<const float4*>(X);
    const float4* __restrict__ T4 = reinterpret_cast<const float4*>(tlut);
    const P8* __restrict__ PK = reinterpret_cast<const P8*>(pk);

    float x0[PPT], x1[PPT], x2[PPT], x3[PPT], xsq[PPT], bestd[PPT];
    int besti[PPT];

    #pragma unroll
    for (int i = 0; i < PPT; ++i) {
        const float4 xv = X4[g + i * stride];
        x0[i] = xv.x; x1[i] = xv.y; x2[i] = xv.z; x3[i] = xv.w;
        // x_sq with numpy rounding: sequential adds of rounded squares
        xsq[i] = __fadd_rn(__fadd_rn(__fadd_rn(__fmul_rn(xv.x, xv.x), __fmul_rn(xv.y, xv.y)),
                                     __fmul_rn(xv.z, xv.z)),
                           __fmul_rn(xv.w, xv.w));
        bestd[i] = __builtin_inff();
        besti[i] = kbase;
    }

    // Round-3-proven lean inner loop: wave-uniform k -> one s_load_dwordx8 per k.
    #pragma unroll 16
    for (int kk = 0; kk < KH; ++kk) {
        const int k = kbase + kk;
        const P8 e = PK[k];
        const float4 c = e.a;
        const float cs = e.b.x;
        #pragma unroll
        for (int i = 0; i < PPT; ++i) {
            // cross: numpy einsum `accum += a*b` with fp-contract -> ascending FMA chain
            float cross = __fmul_rn(x0[i], c.x);
            cross = __fmaf_rn(x1[i], c.y, cross);
            cross = __fmaf_rn(x2[i], c.z, cross);
            cross = __fmaf_rn(x3[i], c.w, cross);
            // (x_sq - 2*cross) + c_sq ; fma(-2,cross,xsq) == rn(xsq - rn(2*cross)) exactly
            float t2 = __fmaf_rn(-2.0f, cross, xsq[i]);
            float d = __fadd_rn(t2, cs);
            // argmin, first occurrence (strict <), ascending k
            besti[i] = (d < bestd[i]) ? k : besti[i];
            bestd[i] = fminf(d, bestd[i]);
        }
    }

    if (q == 1) {
        #pragma unroll
        for (int i = 0; i < PPT; ++i) { sd[i][tt] = bestd[i]; si[i][tt] = besti[i]; }
    }
    __syncthreads();
    if (q == 0) {
        // merge: upper half (larger k) wins only on strict '<' -> np.argmin
        // first-occurrence preserved.
        #pragma unroll
        for (int i = 0; i < PPT; ++i) {
            const float od = sd[i][tt];
            const int   oi = si[i][tt];
            if (od < bestd[i]) { bestd[i] = od; besti[i] = oi; }
        }
        #pragma unroll
        for (int i = 0; i < PPT; ++i) {
            const int p = g + i * stride;
            reinterpret_cast<float4*>(outX)[p] = T4[besti[i]];  // tlut is L1-resident
            outS[p] = (float)besti[i];
        }
    }
}

extern "C" void kernel_launch(void* const* d_in, const int* in_sizes, int n_in,
                              void* d_out, int out_size, void* d_ws, size_t ws_size,
                              hipStream_t stream) {
    const float* X    = (const float*)d_in[0];   // [B,4]
    const float* tlut = (const float*)d_in[1];   // [256,4]
    const int B = in_sizes[0] / 4;

    float* outX = (float*)d_out;          // first B*4 floats: hatX
    float* outS = outX + (size_t)B * 4;   // next B floats: state (as float)

    float* pk = (float*)d_ws;             // 256*8 floats packed codebook

    vq_pack_kernel<<<1, 256, 0, stream>>>(tlut, pk);

    const int groups = B / PPT;           // 262144 point-groups
    const int grid = groups / 256;        // 1024 blocks of 512 threads
    vq_argmin_kernel<<<grid, 512, 0, stream>>>(X, tlut, pk, outX, outS, B);
}